// Round 9
// baseline (228.646 us; speedup 1.0000x reference)
//
#include <hip/hip_runtime.h>

#define N_NODES 50000
#define N_EDGES 800000
#define IN_DIM  128
#define HID_DIM 128
#define OUT_DIM 64

#define NPAD 50176                          // N_NODES rounded up (multiple of 128)
#define CAP  64                             // fixed CSR slots/node (max deg ~36, Poisson(16))
#define GEMM1B ((N_NODES + 63) / 64)        // 782 gemm1 blocks (64 rows each, 256 thr)
#define FILLB (N_EDGES / 256)               // 3125 fill blocks, exact
#define PREPB 24                            // 16 w1t + 8 w2t prep blocks
#define PL1 (N_NODES * 32)                  // ushorts per h1 channel-plane (3.2MB, 4 planes)
#define PL2 (N_NODES * 32)                  // ushorts per h2 channel-plane (3.2MB, 2 planes)

typedef __attribute__((ext_vector_type(8))) short bf16x8;   // 8 bf16 in 4 VGPRs
typedef __attribute__((ext_vector_type(4))) float f32x4;

// float -> bf16 (round-to-nearest-even), as ushort
__device__ __forceinline__ unsigned short f2bf(float f) {
    unsigned u = __float_as_uint(f);
    u += 0x7fffu + ((u >> 16) & 1u);
    return (unsigned short)(u >> 16);
}
// bf16 pair unpack from a uint (little-endian: low ushort first)
__device__ __forceinline__ float bflo(unsigned u) { return __uint_as_float(u << 16); }
__device__ __forceinline__ float bfhi(unsigned u) { return __uint_as_float(u & 0xffff0000u); }

// accumulate one uint4 (8 bf16) into acc[8]
#define ACC8(u)  do { \
    acc[0] += bflo(u.x); acc[1] += bfhi(u.x); \
    acc[2] += bflo(u.y); acc[3] += bfhi(u.y); \
    acc[4] += bflo(u.z); acc[5] += bfhi(u.z); \
    acc[6] += bflo(u.w); acc[7] += bfhi(u.w); } while (0)

// deg -> dinv (reference: deg>0 ? rsqrt(deg) : 0)
__device__ __forceinline__ float deg2dinv(int deg) {
    return (deg > 0) ? rsqrtf((float)deg) : 0.0f;
}

// ---------------- dispatch 2: W^T prep + single-pass atomic CSR fill ----------------
// r7-verified shape: 46us @ 8 VGPR, VALUBusy 0.5% (atomic-bound, fragile to
// co-running work -- r8 measured fusing GEMM1 here costs +20us net). Keep isolated.

__global__ __launch_bounds__(256) void prep_fill_kernel(const int* __restrict__ src,
                                                        const int* __restrict__ dst,
                                                        int* __restrict__ cnt,
                                                        unsigned short* __restrict__ csr_src,
                                                        const float* __restrict__ W1,
                                                        const float* __restrict__ W2,
                                                        unsigned short* __restrict__ w1t,
                                                        unsigned short* __restrict__ w2t) {
    int bid = blockIdx.x;
    int tid = threadIdx.x;
    if (bid < 16) {
        // W1T[c][k] = bf16(W1[k][c]); 128x128 -> 4096 ushort4
        int idx = bid * 256 + tid;
        int c = idx >> 5, k4 = (idx & 31) * 4;
        ushort4 o;
        o.x = f2bf(W1[(k4 + 0) * 128 + c]);
        o.y = f2bf(W1[(k4 + 1) * 128 + c]);
        o.z = f2bf(W1[(k4 + 2) * 128 + c]);
        o.w = f2bf(W1[(k4 + 3) * 128 + c]);
        *(ushort4*)(w1t + c * 128 + k4) = o;
    } else if (bid < PREPB) {
        // W2T[c][k] = bf16(W2[k][c]); 64x128 -> 2048 ushort4
        int idx = (bid - 16) * 256 + tid;
        int c = idx >> 5, k4 = (idx & 31) * 4;
        ushort4 o;
        o.x = f2bf(W2[(k4 + 0) * 64 + c]);
        o.y = f2bf(W2[(k4 + 1) * 64 + c]);
        o.z = f2bf(W2[(k4 + 2) * 64 + c]);
        o.w = f2bf(W2[(k4 + 3) * 64 + c]);
        *(ushort4*)(w2t + c * 128 + k4) = o;
    } else {
        // depth-1 atomic chains: 800k independent atomics (r15 measured win vs depth-4)
        int e = (bid - PREPB) * 256 + tid;   // exact: FILLB*256 == N_EDGES
        int s = src[e], d = dst[e];
        int slot = atomicAdd(&cnt[d], 1);
        if (slot < CAP) csr_src[(d << 6) + slot] = (unsigned short)s;
    }
}

// ---------------- dispatch 3: GEMM1 -> PLANE-MAJOR h1b ----------------
// h1b stored as 4 channel-planes of 32ch (50000*64B = 3.2MB each < 4MB XCD L2):
// per-plane agg1 passes then gather from an L2-resident slab instead of missing
// to L3 on a 12.8MB row-major buffer (r8 subtraction: agg1+agg2 ~ 125us dominated).
// h1b = bf16(dinv_row * (x @ W1))  (r7-verified semantics).

__global__ __launch_bounds__(256) void gemm1_kernel(const float* __restrict__ x,
                                                    const unsigned short* __restrict__ w1t,
                                                    const int* __restrict__ cnt,
                                                    unsigned short* __restrict__ h1b) {
    int gb = blockIdx.x;
    int wave = threadIdx.x >> 6;
    int lane = threadIdx.x & 63;
    int n = lane & 15, quad = lane >> 4;
    int row0 = gb * 64 + wave * 16;

    int arow = row0 + n;
    if (arow >= N_NODES) arow = N_NODES - 1;             // clamp (stores guarded)
    const float* aptr = x + (size_t)arow * 128 + quad * 8;
    const unsigned short* bbase = w1t + (size_t)n * 128 + quad * 8;

    f32x4 acc[8];
#pragma unroll
    for (int t = 0; t < 8; ++t) acc[t] = (f32x4){0.f, 0.f, 0.f, 0.f};

#pragma unroll
    for (int w4 = 0; w4 < 4; ++w4) {
        float4 f0 = *(const float4*)(aptr + w4 * 32);
        float4 f1 = *(const float4*)(aptr + w4 * 32 + 4);
        bf16x8 af;
        af[0] = (short)f2bf(f0.x); af[1] = (short)f2bf(f0.y);
        af[2] = (short)f2bf(f0.z); af[3] = (short)f2bf(f0.w);
        af[4] = (short)f2bf(f1.x); af[5] = (short)f2bf(f1.y);
        af[6] = (short)f2bf(f1.z); af[7] = (short)f2bf(f1.w);
#pragma unroll
        for (int t = 0; t < 8; ++t) {
            bf16x8 bf = *(const bf16x8*)(bbase + (size_t)t * 2048 + w4 * 32);
            acc[t] = __builtin_amdgcn_mfma_f32_16x16x32_bf16(af, bf, acc[t], 0, 0, 0);
        }
    }

#pragma unroll
    for (int r = 0; r < 4; ++r) {
        int row = row0 + quad * 4 + r;
        if (row < N_NODES) {
            float dn = deg2dinv(cnt[row]);
            // channel = n + 16t -> plane t>>1, within-plane ch = n + 16*(t&1)
#pragma unroll
            for (int t = 0; t < 8; ++t)
                h1b[(size_t)(t >> 1) * PL1 + (size_t)row * 32 + n + 16 * (t & 1)]
                    = f2bf(acc[t][r] * dn);
        }
    }
}

// ---------------- dispatch 4: fused agg1 (4 channel-plane passes) + GEMM2 --------
// Per node: 16 threads = 4 edge-groups (e4) x 4 slots (s). Pass p gathers only
// plane p (3.2MB, L2-resident); acc reduced across e4 via shfl_xor(4,8).
// a1 = relu(b1 + dinv_d * sum h1b[src]) assembled in LDS, then MFMA GEMM2 into
// plane-major h2b (2 planes).

#define A1T_STRIDE 136

__global__ __launch_bounds__(256) void agg1_gemm2_fused(const unsigned short* __restrict__ csr_src,
                                                        const int* __restrict__ cnt,
                                                        const float* __restrict__ b1,
                                                        const unsigned short* __restrict__ h1b,
                                                        const unsigned short* __restrict__ w2t,
                                                        unsigned short* __restrict__ h2b) {
    __shared__ unsigned short a1t[16 * A1T_STRIDE];      // 16 x 128 bf16, padded

    int node0 = blockIdx.x * 16;
    int g  = threadIdx.x >> 4;       // node within block
    int r_ = threadIdx.x & 15;
    int e4 = r_ >> 2;                // edge group (0..3)
    int s  = r_ & 3;                 // uint4 slot within 32-ch plane (8 ch each)
    int node = node0 + g;            // always < N_NODES (50000 = 3125*16)
    int start = node << 6;           // fixed-stride CSR row
    int m = cnt[node];
    float dn = deg2dinv(m);
    if (m > CAP) m = CAP;            // never taken; bounds safety

#pragma unroll
    for (int p = 0; p < 4; ++p) {
        const unsigned short* hp = h1b + (size_t)p * PL1;
        float acc[8] = {};
        int j = e4;
        for (; j + 4 < m; j += 8) {
            int s0 = csr_src[start + j];
            int s1 = csr_src[start + j + 4];
            uint4 u0 = *(const uint4*)(hp + (size_t)s0 * 32 + s * 8);
            uint4 u1 = *(const uint4*)(hp + (size_t)s1 * 32 + s * 8);
            ACC8(u0); ACC8(u1);
        }
        if (j < m) {
            int s0 = csr_src[start + j];
            uint4 u0 = *(const uint4*)(hp + (size_t)s0 * 32 + s * 8);
            ACC8(u0);
        }
        // reduce across the 4 edge-groups (lanes +-4, +-8 inside the 16-lane node group)
#pragma unroll
        for (int c = 0; c < 8; ++c) {
            acc[c] += __shfl_xor(acc[c], 4, 64);
            acc[c] += __shfl_xor(acc[c], 8, 64);
        }
        if (e4 == 0) {
            int c0 = p * 32 + s * 8;
            float4 bA = *(const float4*)(b1 + c0);
            float4 bB = *(const float4*)(b1 + c0 + 4);
            ushort4 oA, oB;
            oA.x = f2bf(fmaxf(acc[0] * dn + bA.x, 0.f));
            oA.y = f2bf(fmaxf(acc[1] * dn + bA.y, 0.f));
            oA.z = f2bf(fmaxf(acc[2] * dn + bA.z, 0.f));
            oA.w = f2bf(fmaxf(acc[3] * dn + bA.w, 0.f));
            oB.x = f2bf(fmaxf(acc[4] * dn + bB.x, 0.f));
            oB.y = f2bf(fmaxf(acc[5] * dn + bB.y, 0.f));
            oB.z = f2bf(fmaxf(acc[6] * dn + bB.z, 0.f));
            oB.w = f2bf(fmaxf(acc[7] * dn + bB.w, 0.f));
            ushort4* o = (ushort4*)(a1t + g * A1T_STRIDE + c0);
            o[0] = oA;
            o[1] = oB;
        }
    }
    __syncthreads();

    // Phase 2: MFMA 16 rows x 16 cols per wave; h2b(plane-major) = bf16(dinv*(a1@W2))
    int wave = threadIdx.x >> 6;
    int lane = threadIdx.x & 63;
    int n = lane & 15, quad = lane >> 4;
    const unsigned short* bbase = w2t + (size_t)(wave * 16 + n) * 128 + quad * 8;
    const unsigned short* abase = a1t + (size_t)n * A1T_STRIDE + quad * 8;

    f32x4 c2 = (f32x4){0.f, 0.f, 0.f, 0.f};
#pragma unroll
    for (int w4 = 0; w4 < 4; ++w4) {
        bf16x8 af = *(const bf16x8*)(abase + w4 * 32);
        bf16x8 bf = *(const bf16x8*)(bbase + w4 * 32);
        c2 = __builtin_amdgcn_mfma_f32_16x16x32_bf16(af, bf, c2, 0, 0, 0);
    }

#pragma unroll
    for (int r = 0; r < 4; ++r) {
        int row = node0 + quad * 4 + r;
        float dr = deg2dinv(cnt[row]);
        // channel = wave*16 + n -> plane wave>>1, within-plane ch = (wave&1)*16 + n
        h2b[(size_t)(wave >> 1) * PL2 + (size_t)row * 32 + (wave & 1) * 16 + n]
            = f2bf(c2[r] * dr);
    }
}

// ---------------- dispatch 5: agg2 (2 channel-plane passes) ----------------
// Per node: one wave; 64 lanes = 16 edge-groups (egrp) x 4 slots (s). Pass p
// gathers plane p (3.2MB, L2-resident); reduce across egrp via shfl_xor(4,8,16,32).

__global__ __launch_bounds__(256) void agg2_kernel(const unsigned short* __restrict__ csr_src,
                                                   const int* __restrict__ cnt,
                                                   const float* __restrict__ b2,
                                                   const unsigned short* __restrict__ h2b,
                                                   float* __restrict__ out) {
    int node = blockIdx.x * 4 + (threadIdx.x >> 6);
    if (node >= N_NODES) return;
    int lane = threadIdx.x & 63;
    int egrp = lane >> 2;        // 16 edge groups
    int s    = lane & 3;         // uint4 slot (8 ch each)
    int start = node << 6;       // fixed-stride CSR row
    int m = cnt[node];
    float dn = deg2dinv(m);
    if (m > CAP) m = CAP;

#pragma unroll
    for (int p = 0; p < 2; ++p) {
        const unsigned short* hp = h2b + (size_t)p * PL2;
        float acc[8] = {};
        for (int j = egrp; j < m; j += 16) {
            int s0 = csr_src[start + j];
            uint4 u0 = *(const uint4*)(hp + (size_t)s0 * 32 + s * 8);
            ACC8(u0);
        }
#pragma unroll
        for (int c = 0; c < 8; ++c) {
            acc[c] += __shfl_xor(acc[c], 4, 64);
            acc[c] += __shfl_xor(acc[c], 8, 64);
            acc[c] += __shfl_xor(acc[c], 16, 64);
            acc[c] += __shfl_xor(acc[c], 32, 64);
        }
        if (lane < 4) {          // egrp==0; s = lane
            int c0 = p * 32 + s * 8;
            float4 bA = *(const float4*)(b2 + c0);
            float4 bB = *(const float4*)(b2 + c0 + 4);
            float4 rA, rB;
            rA.x = acc[0] * dn + bA.x;
            rA.y = acc[1] * dn + bA.y;
            rA.z = acc[2] * dn + bA.z;
            rA.w = acc[3] * dn + bA.w;
            rB.x = acc[4] * dn + bB.x;
            rB.y = acc[5] * dn + bB.y;
            rB.z = acc[6] * dn + bB.z;
            rB.w = acc[7] * dn + bB.w;
            float4* o = (float4*)(out + (size_t)node * 64 + c0);
            o[0] = rA;
            o[1] = rB;
        }
    }
}

// ---------------- launch ----------------

extern "C" void kernel_launch(void* const* d_in, const int* in_sizes, int n_in,
                              void* d_out, int out_size, void* d_ws, size_t ws_size,
                              hipStream_t stream) {
    const float* x  = (const float*)d_in[0];
    const int*   ei = (const int*)d_in[1];       // [2, E]: src = ei[0..E), dst = ei[E..2E)
    const float* W1 = (const float*)d_in[2];
    const float* b1 = (const float*)d_in[3];
    const float* W2 = (const float*)d_in[4];
    const float* b2 = (const float*)d_in[5];
    float* out = (float*)d_out;

    const int* src = ei;
    const int* dst = ei + N_EDGES;

    // workspace layout (16B-aligned regions)
    char* ws = (char*)d_ws;
    int*   cnt       = (int*)ws;                                 // NPAD
    unsigned short* csr_src = (unsigned short*)(cnt + NPAD);     // N_NODES*CAP ushort (6.4MB)
    unsigned short* h1b = csr_src + (size_t)N_NODES * CAP;       // 4 planes x 3.2MB
    unsigned short* h2b = h1b + (size_t)4 * PL1;                 // 2 planes x 3.2MB
    unsigned short* w1t = h2b + (size_t)2 * PL2;                 // 128*128 bf16
    unsigned short* w2t = w1t + 128 * 128;                       // 64*128 bf16

    // 1. zero per-node cursors
    (void)hipMemsetAsync(cnt, 0, NPAD * sizeof(int), stream);

    // 2. W^T prep + single-pass atomic CSR fill (isolated: r8 showed fusion hurts)
    prep_fill_kernel<<<PREPB + FILLB, 256, 0, stream>>>(src, dst, cnt, csr_src,
                                                        W1, W2, w1t, w2t);

    // 3. GEMM1 -> plane-major h1b (dinv applied; r7 semantics)
    gemm1_kernel<<<GEMM1B, 256, 0, stream>>>(x, w1t, cnt, h1b);

    // 4. fused: agg1 (4 L2-resident plane passes) + GEMM2 -> plane-major h2b
    agg1_gemm2_fused<<<N_NODES / 16, 256, 0, stream>>>(csr_src, cnt, b1, h1b, w2t, h2b);

    // 5. agg2 (2 L2-resident plane passes)
    agg2_kernel<<<(N_NODES + 3) / 4, 256, 0, stream>>>(csr_src, cnt, b2, h2b, out);
}